// Round 9
// baseline (617.159 us; speedup 1.0000x reference)
//
#include <hip/hip_runtime.h>
#include <cstdint>
#include <cstddef>

#define DEVI __device__ __forceinline__

namespace {

constexpr int T_B = 128;
constexpr int T_N = 48;
constexpr int NP1 = 49;          // n+1 (ghost node)
constexpr int NOUT = T_B * T_N * 4 * NP1;   // 1,204,224 per output tensor

using short8 = __attribute__((ext_vector_type(8))) short;   // 8 bf16
using f32x4  = __attribute__((ext_vector_type(4))) float;

DEVI unsigned rotl(unsigned x, int d) { return (x << d) | (x >> (32 - d)); }

// JAX threefry, PARTITIONABLE mode: counter (0, i), output = x0 ^ x1.
DEVI float gumbel_noise(unsigned idx) {
  unsigned x0 = 0u, x1 = idx;
  const unsigned k0 = 0u, k1 = 42u, k2 = 0x1BD11BDAu ^ 0u ^ 42u;
  x0 += k0; x1 += k1;
#define TF_R(rr) { x0 += x1; x1 = rotl(x1, rr); x1 ^= x0; }
  TF_R(13) TF_R(15) TF_R(26) TF_R(6)   x0 += k1; x1 += k2 + 1u;
  TF_R(17) TF_R(29) TF_R(16) TF_R(24)  x0 += k2; x1 += k0 + 2u;
  TF_R(13) TF_R(15) TF_R(26) TF_R(6)   x0 += k0; x1 += k1 + 3u;
  TF_R(17) TF_R(29) TF_R(16) TF_R(24)  x0 += k1; x1 += k2 + 4u;
  TF_R(13) TF_R(15) TF_R(26) TF_R(6)   x0 += k2; x1 += k0 + 5u;
#undef TF_R
  const unsigned bits = x0 ^ x1;
  float u = __uint_as_float((bits >> 9) | 0x3f800000u) - 1.0f;
  u = fmaxf(u, 0.0f);
  const float ex = -log1pf(-u);
  return -logf(ex);
}

// fp32 -> bf16 round-to-nearest-even
DEVI unsigned short f2bf(float f) {
  const unsigned u = __float_as_uint(f);
  return (unsigned short)((u + 0x7fffu + ((u >> 16) & 1u)) >> 16);
}
DEVI float bf2f(unsigned short u) { return __uint_as_float(((unsigned)u) << 16); }

#define DOT4(Aa, Bb) ((Aa).x * (Bb).x + (Aa).y * (Bb).y + (Aa).z * (Bb).z + (Aa).w * (Bb).w)

// Arena byte offsets (single overlaid arena; liveness commented per phase)
constexpr int FH  = 0;       // feat hi ushort[64][104] = 13312   (ph0-1)
constexpr int FL  = 13312;   // feat lo                  (end 26624)
constexpr int EHO = 0;       // E hi [64 rows][256 B] swizzled    (ph1-2, over feat)
constexpr int ELO = 16384;   // E lo                     (end 32768)
constexpr int AMO = 32768;   // sAM f32[48][48] = 9216            (ph0 only)
constexpr int SLN = 32768;   // sLN f32[4][64][2] = 2048          (ph1, over sAM)
constexpr int QBO = 0;       // Qb bf16 [4][64][32] = 16384       (ph2-3a, over E hi)
constexpr int KBO = 16384;   // Kb bf16 [4][64][32] = 16384       (ph2-3a, over E lo)
constexpr int VTO = 32768;   // VT bf16 [4][32][64] = 16384       (ph2-3b, over sAM) end 49152
constexpr int PBO = 0;       // P  bf16 [4][64][64] = 32768       (ph3a-b, over Qb+Kb)
constexpr int A2O = 0;       // A2 f32  [4][64][34] = 34816       (ph3b-c, over P/VT0)
constexpr int W1O = 34816;   // W1t f32 [32][32] = 4096           (ph3c, over dead VT)
constexpr int ARENA_BYTES = 49152;

}  // namespace

// Transposed bf16 hi/lo weights (L2-resident).
__device__ __align__(16) unsigned short g_Wt[2 * 384 * 128];
__device__ __align__(16) unsigned short g_We[2 * 128 * 96];

__global__ void convert_weights_kernel(const float* __restrict__ Wqkv,
                                       const float* __restrict__ Wemb) {
  const int tid = blockIdx.x * 256 + threadIdx.x;
  if (tid < 49152) {
    const int n = tid >> 7, k = tid & 127;
    const float w = Wqkv[k * 384 + n];
    const unsigned short hi = f2bf(w);
    g_Wt[n * 128 + k] = hi;
    g_Wt[49152 + n * 128 + k] = f2bf(w - bf2f(hi));
  } else if (tid < 61440) {
    const int t2 = tid - 49152;
    const int c = t2 / 96, k = t2 - c * 96;
    const float w = Wemb[k * 128 + c];
    const unsigned short hi = f2bf(w);
    g_We[c * 96 + k] = hi;
    g_We[12288 + c * 96 + k] = f2bf(w - bf2f(hi));
  }
}

// One block per (batch, target). All big math on MFMA; LDS arena 48 KB
// overlaid -> ~50.2 KB total -> 3 blocks/CU (LDS-governed).
// launch_bounds(256,2): R8's (256,3) made the allocator target 84 VGPRs and
// spill the MFMA accumulators (~245 MB scratch traffic). (256,2) gives a
// 256-reg budget; actual use ~130-160 keeps 3 waves/EU via LDS anyway.
//  0: masks; feat bf16 hi/lo; pads zeroed
//  1: E = LN(feat @ Wemb) MFMA split-bf16; E overwrites feat post-barrier
//  2: qkv MFMA split-bf16 -> Qb/Kb bf16 (swizzled k), VT bf16 (swizzled j,
//     fully pre-zeroed: pad j cols MUST be 0 as MFMA B-operand)
//  3a: S = Q·K^T via MFMA (wave=head); BARRIER (all Q/K reads drained —
//      P overlays other heads' Q/K, airtight now); masked softmax on
//      C-frags; P stored NORMALIZED (p/ls) bf16 -> no linv carried
//  3b: A2 = P·V via MFMA; barrier; A2 fp32 -> LDS; stage W1t
//  3c: per-lane gating MLP + em softmax + threefry gumbel
__global__ __launch_bounds__(256, 2) void edge_selector_kernel(
    const float* __restrict__ x, const float* __restrict__ A,
    const float* __restrict__ amask, const float* __restrict__ Wemb,
    const float* __restrict__ bemb, const float* __restrict__ gamma_,
    const float* __restrict__ beta_, const float* __restrict__ Wqkv,
    const float* __restrict__ bqkv, const float* __restrict__ W1g,
    const float* __restrict__ b1g, const float* __restrict__ W2g,
    const float* __restrict__ b2g, float* __restrict__ out) {
  __shared__ __align__(16) unsigned char ARENA[ARENA_BYTES];
  __shared__ float sM[64];     // mask row of tg, ghost=1, pads 49-63 = 0
  __shared__ float sMp[48];
  __shared__ float sB1[32];
  __shared__ float sW2s[32];
  __shared__ float sB2;

  unsigned short* const featH = (unsigned short*)(ARENA + FH);
  unsigned short* const featL = (unsigned short*)(ARENA + FL);
  float* const sAM  = (float*)(ARENA + AMO);
  float* const sLNa = (float*)(ARENA + SLN);

  const int t  = threadIdx.x;
  const int tg = blockIdx.x;
  const int bb = blockIdx.y;

  // ---------------- phase 0a: masks + small weights + pad zero -----------
  for (int idx = t; idx < 48 * 48; idx += 256) sAM[idx] = amask[bb * 2304 + idx];
  {
    unsigned* zh = (unsigned*)(ARENA + FH + 49 * 208);
    unsigned* zl = (unsigned*)(ARENA + FL + 49 * 208);
    for (int idx = t; idx < 780; idx += 256) { zh[idx] = 0u; zl[idx] = 0u; }
  }
  if (t >= 49 && t < 64) sM[t] = 0.f;   // pads
  if (t < 32) { sB1[t] = b1g[t]; sW2s[t] = W2g[t]; }
  if (t == 0) sB2 = b2g[0];
  __syncthreads();
  if (t < 48) {
    float s = 0.f;
    for (int j = 0; j < 48; ++j) s += sAM[t * 48 + j];
    sMp[t] = (s > 0.f) ? 1.f : 0.f;
    sM[t] = sAM[tg * 48 + t];
  }
  if (t == 48) sM[48] = 1.f;   // ghost always attendable
  __syncthreads();

  // ---------------- phase 0b: feat -> bf16 hi/lo -------------------------
  {
    const float mt_ = sMp[tg];
#define WFB(col, val) { const unsigned short hh_ = f2bf(val);            \
    featH[nb * 104 + (col)] = hh_;                                       \
    featL[nb * 104 + (col)] = f2bf((val) - bf2f(hh_)); }
    for (int idx = t; idx < NP1 * 32; idx += 256) {
      const int nb = idx >> 5, e = idx & 31;
      const float xt = x[(bb * 48 + tg) * 32 + e] * mt_;
      float xv = 0.f, av = 0.f;
      if (nb < 48) {
        xv = x[(bb * 48 + nb) * 32 + e] * sMp[nb];
        av = A[(((bb * 48 + nb) * 48) + tg) * 32 + e] * sM[nb];
      }
      WFB(e, xv) WFB(32 + e, xt) WFB(64 + e, av)
    }
#undef WFB
  }
  __syncthreads();

  const int w  = t >> 6;
  const int l  = t & 63;
  const int lm = l & 15, lg = l >> 4;

  // ---------------- phase 1: E = LN(feat @ Wemb + b) via MFMA ------------
  {
    f32x4 eacc[4][2];
#pragma unroll
    for (int mt = 0; mt < 4; ++mt)
#pragma unroll
      for (int nt = 0; nt < 2; ++nt) eacc[mt][nt] = (f32x4){0.f, 0.f, 0.f, 0.f};

#pragma unroll
    for (int ks = 0; ks < 3; ++ks) {
      short8 fh[4], fl[4];
#pragma unroll
      for (int mt = 0; mt < 4; ++mt) {
        const int so = (mt * 16 + lm) * 104 + ks * 32 + lg * 8;
        fh[mt] = *(const short8*)&featH[so];
        fl[mt] = *(const short8*)&featL[so];
      }
#pragma unroll
      for (int nt = 0; nt < 2; ++nt) {
        const int kid = ((w * 2 + nt) * 16 + lm) * 96 + ks * 32 + lg * 8;
        const short8 bh = *(const short8*)&g_We[kid];
        const short8 bl = *(const short8*)&g_We[12288 + kid];
#pragma unroll
        for (int mt = 0; mt < 4; ++mt) {
          eacc[mt][nt] = __builtin_amdgcn_mfma_f32_16x16x32_bf16(fh[mt], bh, eacc[mt][nt], 0, 0, 0);
          eacc[mt][nt] = __builtin_amdgcn_mfma_f32_16x16x32_bf16(fl[mt], bh, eacc[mt][nt], 0, 0, 0);
          eacc[mt][nt] = __builtin_amdgcn_mfma_f32_16x16x32_bf16(fh[mt], bl, eacc[mt][nt], 0, 0, 0);
        }
      }
    }

    const float b0 = bemb[(w * 2 + 0) * 16 + lm];
    const float b1 = bemb[(w * 2 + 1) * 16 + lm];
#pragma unroll
    for (int mt = 0; mt < 4; ++mt)
#pragma unroll
      for (int r = 0; r < 4; ++r) {
        const float v0 = eacc[mt][0][r] + b0;
        const float v1 = eacc[mt][1][r] + b1;
        float s  = v0 + v1;
        float qs = v0 * v0 + v1 * v1;
#pragma unroll
        for (int md = 8; md; md >>= 1) {
          s  += __shfl_xor(s, md);
          qs += __shfl_xor(qs, md);
        }
        if (lm == 0) {
          const int row = mt * 16 + lg * 4 + r;
          sLNa[(w * 64 + row) * 2 + 0] = s;
          sLNa[(w * 64 + row) * 2 + 1] = qs;
        }
      }
    __syncthreads();   // feat reads done everywhere; sLN visible

    const int c0 = (w * 2) * 16 + lm, c1 = c0 + 16;
    const float g0 = gamma_[c0], g1 = gamma_[c1];
    const float be0 = beta_[c0], be1 = beta_[c1];
#pragma unroll
    for (int mt = 0; mt < 4; ++mt)
#pragma unroll
      for (int r = 0; r < 4; ++r) {
        const int row = mt * 16 + lg * 4 + r;
        const float s  = sLNa[row * 2 + 0] + sLNa[(64 + row) * 2 + 0] +
                         sLNa[(128 + row) * 2 + 0] + sLNa[(192 + row) * 2 + 0];
        const float qs = sLNa[row * 2 + 1] + sLNa[(64 + row) * 2 + 1] +
                         sLNa[(128 + row) * 2 + 1] + sLNa[(192 + row) * 2 + 1];
        const float mu  = s * (1.0f / 128.0f);
        const float var = qs * (1.0f / 128.0f) - mu * mu;
        const float rs  = 1.0f / sqrtf(var + 1e-5f);
        const float o0 = (eacc[mt][0][r] + b0 - mu) * rs * g0 + be0;
        const float o1 = (eacc[mt][1][r] + b1 - mu) * rs * g1 + be1;
        const int sw = (row & 3) << 4;
        const unsigned short h0 = f2bf(o0);
        const unsigned short h1 = f2bf(o1);
        *(unsigned short*)(ARENA + EHO + row * 256 + ((c0 * 2) ^ sw)) = h0;
        *(unsigned short*)(ARENA + ELO + row * 256 + ((c0 * 2) ^ sw)) = f2bf(o0 - bf2f(h0));
        *(unsigned short*)(ARENA + EHO + row * 256 + ((c1 * 2) ^ sw)) = h1;
        *(unsigned short*)(ARENA + ELO + row * 256 + ((c1 * 2) ^ sw)) = f2bf(o1 - bf2f(h1));
      }
    // zero E pad rows 49-63 (hi + lo): 960 dwords each
    for (int idx = t; idx < 1920; idx += 256) {
      const int buf = (idx >= 960) ? ELO : EHO;
      const int k2 = (idx >= 960) ? idx - 960 : idx;
      *(unsigned*)(ARENA + buf + (49 + (k2 >> 6)) * 256 + (k2 & 63) * 4) = 0u;
    }
  }
  __syncthreads();

  // ---------------- phase 2: qkv = E @ Wqkv via MFMA (split bf16) --------
  {
    const float SC = 0.17677669529663687f;  // 1/sqrt(32)

    f32x4 acc[4][6];
#pragma unroll
    for (int mt = 0; mt < 4; ++mt)
#pragma unroll
      for (int nt = 0; nt < 6; ++nt) acc[mt][nt] = (f32x4){0.f, 0.f, 0.f, 0.f};

#pragma unroll
    for (int ks = 0; ks < 4; ++ks) {
      short8 ah[4], alo[4];
#pragma unroll
      for (int mt = 0; mt < 4; ++mt) {
        const int row = mt * 16 + lm;
        const int off = (ks * 64 + lg * 16) ^ ((row & 3) << 4);
        ah[mt]  = *(const short8*)(ARENA + EHO + row * 256 + off);
        alo[mt] = *(const short8*)(ARENA + ELO + row * 256 + off);
      }
#pragma unroll
      for (int nt = 0; nt < 6; ++nt) {
        const int kid = ((w * 6 + nt) * 16 + lm) * 128 + ks * 32 + lg * 8;
        const short8 bh = *(const short8*)&g_Wt[kid];
        const short8 bl = *(const short8*)&g_Wt[49152 + kid];
#pragma unroll
        for (int mt = 0; mt < 4; ++mt) {
          acc[mt][nt] = __builtin_amdgcn_mfma_f32_16x16x32_bf16(ah[mt],  bh, acc[mt][nt], 0, 0, 0);
          acc[mt][nt] = __builtin_amdgcn_mfma_f32_16x16x32_bf16(alo[mt], bh, acc[mt][nt], 0, 0, 0);
          acc[mt][nt] = __builtin_amdgcn_mfma_f32_16x16x32_bf16(ah[mt],  bl, acc[mt][nt], 0, 0, 0);
        }
      }
    }

    // pre-zero VT (over dead sAM/sLN; NOT over E) before the barrier
    { unsigned* vz = (unsigned*)(ARENA + VTO);
      for (int idx = t; idx < 4096; idx += 256) vz[idx] = 0u; }
    __syncthreads();   // all E reads done; VT zero visible

    float bias[6];
#pragma unroll
    for (int nt = 0; nt < 6; ++nt) bias[nt] = bqkv[(w * 6 + nt) * 16 + lm];

#pragma unroll
    for (int nt = 0; nt < 6; ++nt) {
      const int ntg = w * 6 + nt;
      const int c = ntg * 16 + lm;
#pragma unroll
      for (int mt = 0; mt < 4; ++mt)
#pragma unroll
        for (int r = 0; r < 4; ++r) {
          const int nb = mt * 16 + lg * 4 + r;
          if (nb < NP1) {
            const float v = acc[mt][nt][r] + bias[nt];
            if (ntg < 8) {            // Q: scaled bf16, k-swizzled
              const int h = c >> 5, k = c & 31;
              *(unsigned short*)(ARENA + QBO +
                ((h * 64 + nb) * 32 + (k ^ ((nb & 3) << 3))) * 2) = f2bf(v * SC);
            } else if (ntg < 16) {    // K: bf16, k-swizzled
              const int cc = c - 128, h = cc >> 5, k = cc & 31;
              *(unsigned short*)(ARENA + KBO +
                ((h * 64 + nb) * 32 + (k ^ ((nb & 3) << 3))) * 2) = f2bf(v);
            } else {                  // V^T: bf16, j-swizzled
              const int cc = c - 256, h = cc >> 5, e = cc & 31;
              *(unsigned short*)(ARENA + VTO +
                ((h * 32 + e) * 64 + (nb ^ ((e & 7) << 3))) * 2) = f2bf(v);
            }
          }
        }
    }
  }
  __syncthreads();

  // ---------------- phase 3a: S = Q·K^T (MFMA) + softmax -> P ------------
  const int wh = w;   // wave = head
  {
    f32x4 sacc[4][4];
#pragma unroll
    for (int mt = 0; mt < 4; ++mt)
#pragma unroll
      for (int nt = 0; nt < 4; ++nt) sacc[mt][nt] = (f32x4){0.f, 0.f, 0.f, 0.f};

    const int koff = ((lg * 8) ^ ((lm & 3) << 3)) * 2;
    short8 qa[4];
#pragma unroll
    for (int mt = 0; mt < 4; ++mt)
      qa[mt] = *(const short8*)(ARENA + QBO + wh * 4096 + (mt * 16 + lm) * 64 + koff);
#pragma unroll
    for (int nt = 0; nt < 4; ++nt) {
      const short8 kb = *(const short8*)(ARENA + KBO + wh * 4096 + (nt * 16 + lm) * 64 + koff);
#pragma unroll
      for (int mt = 0; mt < 4; ++mt)
        sacc[mt][nt] = __builtin_amdgcn_mfma_f32_16x16x32_bf16(qa[mt], kb, sacc[mt][nt], 0, 0, 0);
    }
    __syncthreads();   // ALL waves' Q/K reads drained; P may overlay Qb/Kb

    const float NINF = -__builtin_huge_valf();
    const int jj0 = lm, jj1 = 16 + lm, jj2 = 32 + lm, jj3 = 48 + lm;
    const bool jv0 = sM[jj0] > 0.f;
    const bool jv1 = sM[jj1] > 0.f;
    const bool jv2 = sM[jj2] > 0.f;
    const bool jp3 = jj3 < 49;                 // only lm==0 (ghost col)
    const bool jv3 = jp3 && (sM[jj3] > 0.f);

#pragma unroll
    for (int mt = 0; mt < 4; ++mt) {
#pragma unroll
      for (int r = 0; r < 4; ++r) {
        const int ii = mt * 16 + lg * 4 + r;
        const bool iok = (ii < 49) && (sM[ii] > 0.f);
        const float s0 = (iok && jv0) ? sacc[mt][0][r] : -1e9f;
        const float s1 = (iok && jv1) ? sacc[mt][1][r] : -1e9f;
        const float s2 = (iok && jv2) ? sacc[mt][2][r] : -1e9f;
        const float s3 = jp3 ? ((iok && jv3) ? sacc[mt][3][r] : -1e9f) : NINF;
        float mx = fmaxf(fmaxf(s0, s1), fmaxf(s2, s3));
#pragma unroll
        for (int md = 8; md; md >>= 1) mx = fmaxf(mx, __shfl_xor(mx, md));
        const float p0 = expf(s0 - mx);
        const float p1 = expf(s1 - mx);
        const float p2 = expf(s2 - mx);
        const float p3 = expf(s3 - mx);       // pad j -> exp(-inf) = 0
        float ls = p0 + p1 + p2 + p3;
#pragma unroll
        for (int md = 8; md; md >>= 1) ls += __shfl_xor(ls, md);
        const float rls = 1.0f / ls;          // P stored pre-normalized
        const int pb = PBO + wh * 8192 + ii * 128;
        const int sw = (ii & 7) << 3;
        *(unsigned short*)(ARENA + pb + ((jj0 ^ sw) << 1)) = f2bf(p0 * rls);
        *(unsigned short*)(ARENA + pb + ((jj1 ^ sw) << 1)) = f2bf(p1 * rls);
        *(unsigned short*)(ARENA + pb + ((jj2 ^ sw) << 1)) = f2bf(p2 * rls);
        *(unsigned short*)(ARENA + pb + ((jj3 ^ sw) << 1)) = f2bf(p3 * rls);
      }
    }
  }
  __syncthreads();   // P visible to all waves

  // ---------------- phase 3b: A2 = P·V (MFMA) -> LDS ---------------------
  {
    f32x4 pacc[4][2];
#pragma unroll
    for (int mt = 0; mt < 4; ++mt)
#pragma unroll
      for (int nt = 0; nt < 2; ++nt) pacc[mt][nt] = (f32x4){0.f, 0.f, 0.f, 0.f};

#pragma unroll
    for (int ks = 0; ks < 2; ++ks) {
      const int jsw = ((ks * 32 + lg * 8) ^ ((lm & 7) << 3)) * 2;
      short8 pa[4];
#pragma unroll
      for (int mt = 0; mt < 4; ++mt)
        pa[mt] = *(const short8*)(ARENA + PBO + wh * 8192 + (mt * 16 + lm) * 128 + jsw);
#pragma unroll
      for (int nt = 0; nt < 2; ++nt) {
        const short8 vb = *(const short8*)(ARENA + VTO + wh * 4096 + (nt * 16 + lm) * 128 + jsw);
#pragma unroll
        for (int mt = 0; mt < 4; ++mt)
          pacc[mt][nt] = __builtin_amdgcn_mfma_f32_16x16x32_bf16(pa[mt], vb, pacc[mt][nt], 0, 0, 0);
      }
    }
    __syncthreads();   // P/VT reads done everywhere -> A2/W1t may overlay

    float* const A2f = (float*)(ARENA + A2O);
#pragma unroll
    for (int mt = 0; mt < 4; ++mt)
#pragma unroll
      for (int nt = 0; nt < 2; ++nt)
#pragma unroll
        for (int r = 0; r < 4; ++r) {
          const int ii = mt * 16 + lg * 4 + r;
          A2f[(wh * 64 + ii) * 34 + nt * 16 + lm] = pacc[mt][nt][r];
        }
    float* const w1t = (float*)(ARENA + W1O);
    for (int idx = t; idx < 1024; idx += 256) {
      const int e = idx >> 5, f = idx & 31;
      w1t[f * 32 + e] = W1g[idx];
    }
  }
  __syncthreads();

  // ---------------- phase 3c: gating + em + sampled ----------------------
  {
    const int lane = l;
    const bool act = lane < NP1;
    const int i    = act ? lane : 0;
    const float* const A2r = (const float*)(ARENA + A2O) + (wh * 64 + i) * 34;
    const float* const w1t = (const float*)(ARENA + W1O);

    float4 a0, a1, a2, a3, a4, a5, a6, a7;
#define LDA2(Q, E) { const float2 u0 = *(const float2*)&A2r[E];          \
                     const float2 u1 = *(const float2*)&A2r[(E) + 2];    \
                     Q.x = u0.x; Q.y = u0.y; Q.z = u1.x; Q.w = u1.y; }
    LDA2(a0, 0)  LDA2(a1, 4)  LDA2(a2, 8)  LDA2(a3, 12)
    LDA2(a4, 16) LDA2(a5, 20) LDA2(a6, 24) LDA2(a7, 28)
#undef LDA2

    const float mi = act ? sM[i] : 0.f;

    float s2 = sB2;
    for (int f = 0; f < 32; ++f) {
      const float4* wr = (const float4*)&w1t[f * 32];
      const float4 w0 = wr[0], w1 = wr[1], w2 = wr[2], w3 = wr[3];
      const float4 w4 = wr[4], w5 = wr[5], w6 = wr[6], w7 = wr[7];
      float g = sB1[f] +
          DOT4(a0, w0) + DOT4(a1, w1) + DOT4(a2, w2) + DOT4(a3, w3) +
          DOT4(a4, w4) + DOT4(a5, w5) + DOT4(a6, w6) + DOT4(a7, w7);
      s2 += fmaxf(g, 0.f) * sW2s[f];
    }

    const float v0s = act ? s2 : -1e30f;
    float mx2 = v0s;
#pragma unroll
    for (int md = 32; md; md >>= 1) mx2 = fmaxf(mx2, __shfl_xor(mx2, md));
    float p = act ? expf(v0s - mx2) : 0.f;
    float ps = p;
#pragma unroll
    for (int md = 32; md; md >>= 1) ps += __shfl_xor(ps, md);
    float em = (p / ps) * mi;
    float es = em;
#pragma unroll
    for (int md = 32; md; md >>= 1) es += __shfl_xor(es, md);
    em = em / (es + 1e-10f);

    const int base = ((bb * 48 + tg) * 4 + wh) * 49;
    if (act) out[base + lane] = em;

    const float lg2 = logf(em + 1e-10f);
    const float gn = gumbel_noise((unsigned)(base + lane));
    const float z = act ? (lg2 + gn) : -1e30f;
    float mx3 = z;
#pragma unroll
    for (int md = 32; md; md >>= 1) mx3 = fmaxf(mx3, __shfl_xor(mx3, md));
    float p3 = act ? expf(z - mx3) : 0.f;
    float ps3 = p3;
#pragma unroll
    for (int md = 32; md; md >>= 1) ps3 += __shfl_xor(ps3, md);
    if (act) out[NOUT + base + lane] = p3 / ps3;
  }
}

extern "C" void kernel_launch(void* const* d_in, const int* in_sizes, int n_in,
                              void* d_out, int out_size, void* d_ws, size_t ws_size,
                              hipStream_t stream) {
  (void)in_sizes; (void)n_in; (void)out_size; (void)d_ws; (void)ws_size;
  const float* x    = (const float*)d_in[0];
  const float* A    = (const float*)d_in[1];
  const float* am   = (const float*)d_in[2];
  const float* Wemb = (const float*)d_in[3];
  const float* bemb = (const float*)d_in[4];
  const float* gm   = (const float*)d_in[5];
  const float* bt   = (const float*)d_in[6];
  const float* Wqkv = (const float*)d_in[7];
  const float* bqkv = (const float*)d_in[8];
  const float* W1   = (const float*)d_in[9];
  const float* b1   = (const float*)d_in[10];
  const float* W2   = (const float*)d_in[11];
  const float* b2   = (const float*)d_in[12];
  convert_weights_kernel<<<240, 256, 0, stream>>>(Wqkv, Wemb);
  dim3 grid(T_N, T_B);
  edge_selector_kernel<<<grid, 256, 0, stream>>>(
      x, A, am, Wemb, bemb, gm, bt, Wqkv, bqkv, W1, b1, W2, b2, (float*)d_out);
}